// Round 2
// baseline (205.293 us; speedup 1.0000x reference)
//
#include <hip/hip_runtime.h>

#define SEQ 4096
#define DM  2048
#define DH  128
#define NSPLIT 8

typedef __attribute__((ext_vector_type(8))) short bf16x8;
typedef __attribute__((ext_vector_type(4))) short short4v;
typedef __attribute__((ext_vector_type(4))) float f32x4;

__device__ inline short f2bf(float f) {
    union { float f; unsigned u; } x; x.f = f;
    unsigned r = x.u + 0x7fffu + ((x.u >> 16) & 1u);
    return (short)(r >> 16);
}

__device__ inline float fexp2(float f) { return __builtin_amdgcn_exp2f(f); }

// Barrier that does NOT drain outstanding global->VGPR loads (only LDS ops).
// __syncthreads() would emit s_waitcnt vmcnt(0) and collapse register prefetch.
__device__ inline void lds_barrier() {
    asm volatile("s_waitcnt lgkmcnt(0)\n\ts_barrier" ::: "memory");
}

// ---------------- W fp32 -> bf16 pre-convert. grid 768, block 256. Wbf[3][128][2048]
__global__ __launch_bounds__(256) void convw_kernel(
    const float* __restrict__ wq, const float* __restrict__ wk, const float* __restrict__ wv,
    short* __restrict__ Wbf)
{
    int idx = blockIdx.x * 256 + threadIdx.x;
    int mat = idx >> 16;
    int off = (idx & 65535) * 4;
    const float* W = (mat == 0) ? wq : (mat == 1) ? wk : wv;
    float4 v = *reinterpret_cast<const float4*>(W + off);
    short4v s = { f2bf(v.x), f2bf(v.y), f2bf(v.z), f2bf(v.w) };
    *reinterpret_cast<short4v*>(Wbf + (size_t)mat * DH * DM + off) = s;
}

// ---------------- Projection, full-K, direct bf16 epilogue (bias fused).
// grid (256, 3), block 256 (4 waves). Block tile: 16 rows x 128 cols, K=2048,
// BK=64 (32 chunks, fully unrolled). W fragments are loaded DIRECTLY from
// global (L2-resident bf16) with depth-2 register prefetch -- no W LDS staging.
// A goes through a double-buffered 2.3KB LDS tile (fp32->bf16 convert once),
// depth-4 register prefetch, ONE vmcnt-preserving barrier per chunk.
// VGPR budget: abuf 16 + wfrag 32 + acc 8 + addr ~20 = ~76 < 128 cap.
__global__ __launch_bounds__(256, 4) void proj_kernel(
    const float* __restrict__ inq, const float* __restrict__ ink, const float* __restrict__ inv,
    const short* __restrict__ Wbf,
    const float* __restrict__ bq, const float* __restrict__ bk, const float* __restrict__ bv,
    short* __restrict__ Qws, short* __restrict__ Kws, short* __restrict__ Vtws)
{
    const int mat = blockIdx.y;
    const float* A    = (mat == 0) ? inq : (mat == 1) ? ink : inv;
    const float* bias = (mat == 0) ? bq  : (mat == 1) ? bk  : bv;

    const int tid  = threadIdx.x;
    const int lane = tid & 63;
    const int w    = tid >> 6;
    const int g    = lane >> 4;
    const int c16  = lane & 15;
    const int i0   = blockIdx.x * 16;

    __shared__ short Alds[2][16][72];

    // A staging: each thread owns one float4 per chunk.
    const int ar = tid >> 4, ac = (tid & 15) * 4;
    const float* Aload = A + (size_t)(i0 + ar) * DM + ac;

    // W fragment base: lane (g,c16) reads W[w*32 + n*16 + c16][k + g*8 .. +8]
    const short* Wbase = Wbf + (size_t)mat * DH * DM + (size_t)(w * 32 + c16) * DM + g * 8;

    f32x4 acc[2];
    acc[0] = (f32x4){0.f, 0.f, 0.f, 0.f};
    acc[1] = (f32x4){0.f, 0.f, 0.f, 0.f};

    float4  abuf[4];      // depth 4 (HBM)
    bf16x8  wfrag[2][4];  // depth 2 (L2), frag index = n*2 + kk

    #pragma unroll
    for (int d = 0; d < 4; d++)
        abuf[d] = *reinterpret_cast<const float4*>(Aload + d * 64);
    #pragma unroll
    for (int d = 0; d < 2; d++)
        #pragma unroll
        for (int n = 0; n < 2; n++)
            #pragma unroll
            for (int kk = 0; kk < 2; kk++)
                wfrag[d][n * 2 + kk] = *reinterpret_cast<const bf16x8*>(
                    Wbase + (size_t)n * 16 * DM + d * 64 + kk * 32);

    // stage chunk 0, then refill abuf[0] with chunk 4
    {
        float4 v = abuf[0];
        short4v sv = { f2bf(v.x), f2bf(v.y), f2bf(v.z), f2bf(v.w) };
        *reinterpret_cast<short4v*>(&Alds[0][ar][ac]) = sv;
        abuf[0] = *reinterpret_cast<const float4*>(Aload + 4 * 64);
    }
    lds_barrier();

    #pragma unroll
    for (int c = 0; c < 32; c++) {
        // stage chunk c+1 into the other buffer, refill its abuf slot with c+5
        if (c + 1 < 32) {
            float4 v = abuf[(c + 1) & 3];
            short4v sv = { f2bf(v.x), f2bf(v.y), f2bf(v.z), f2bf(v.w) };
            *reinterpret_cast<short4v*>(&Alds[(c + 1) & 1][ar][ac]) = sv;
        }
        if (c + 5 < 32)
            abuf[(c + 1) & 3] = *reinterpret_cast<const float4*>(Aload + (c + 5) * 64);

        // compute chunk c
        #pragma unroll
        for (int kk = 0; kk < 2; kk++) {
            bf16x8 af = *reinterpret_cast<const bf16x8*>(&Alds[c & 1][c16][kk * 32 + g * 8]);
            #pragma unroll
            for (int n = 0; n < 2; n++)
                acc[n] = __builtin_amdgcn_mfma_f32_16x16x32_bf16(
                    af, wfrag[c & 1][n * 2 + kk], acc[n], 0, 0, 0);
        }

        // refill W fragments for chunk c+2
        if (c + 2 < 32) {
            #pragma unroll
            for (int n = 0; n < 2; n++)
                #pragma unroll
                for (int kk = 0; kk < 2; kk++)
                    wfrag[c & 1][n * 2 + kk] = *reinterpret_cast<const bf16x8*>(
                        Wbase + (size_t)n * 16 * DM + (c + 2) * 64 + kk * 32);
        }

        if (c + 1 < 32) lds_barrier();
    }

    const int row0 = i0 + g * 4;
    if (mat < 2) {
        short* outp = (mat == 0) ? Qws : Kws;
        #pragma unroll
        for (int n = 0; n < 2; n++) {
            int col = w * 32 + n * 16 + c16;
            float b = bias[col];
            #pragma unroll
            for (int r = 0; r < 4; r++)
                outp[(size_t)(row0 + r) * DH + col] = f2bf(acc[n][r] + b);
        }
    } else {
        #pragma unroll
        for (int n = 0; n < 2; n++) {
            int col = w * 32 + n * 16 + c16;
            float b = bias[col];
            short4v o = { f2bf(acc[n][0] + b), f2bf(acc[n][1] + b),
                          f2bf(acc[n][2] + b), f2bf(acc[n][3] + b) };
            *reinterpret_cast<short4v*>(Vtws + (size_t)col * SEQ + row0) = o;
        }
    }
}

// ---------------- Flash attention, block-cooperative K/V staging, vmcnt-preserving
// barriers. grid (64, NSPLIT), block 256 (4 waves).
__global__ __launch_bounds__(256) void flash_kernel(
    const short* __restrict__ Qws, const short* __restrict__ Kws, const short* __restrict__ Vtws,
    float* __restrict__ Opart, float* __restrict__ mpart, float* __restrict__ lpart)
{
    const int qb = blockIdx.x;
    const int y  = blockIdx.y;
    const int tid = threadIdx.x;
    const int w    = tid >> 6;
    const int lane = tid & 63;
    const int g = lane >> 4, c16 = lane & 15;
    const int i0 = qb * 64 + w * 16;

    __shared__ short Klds[64][136];
    __shared__ short Vlds[128][72];
    __shared__ short Slds[4][16][72];

    const int kkey = tid >> 2,  kdim = (tid & 3) * 32;
    const int vdim = tid >> 1,  vkey = (tid & 1) * 32;

    bf16x8 kreg[4], vreg[4];

    bf16x8 qf[4];
    #pragma unroll
    for (int kk = 0; kk < 4; kk++)
        qf[kk] = *reinterpret_cast<const bf16x8*>(Qws + (size_t)(i0 + c16) * DH + kk * 32 + g * 8);

    float m[4], lsum[4];
    f32x4 O[8];
    #pragma unroll
    for (int r = 0; r < 4; r++) { m[r] = -__builtin_inff(); lsum[r] = 0.f; }
    #pragma unroll
    for (int c = 0; c < 8; c++) O[c] = (f32x4){0.f, 0.f, 0.f, 0.f};

    const float C = 0.03188448666f;      // log2(e)/sqrt(2048)

    if (qb >= y) {
        {
            const int j0 = y * 64;
            #pragma unroll
            for (int j = 0; j < 4; j++) {
                kreg[j] = *reinterpret_cast<const bf16x8*>(
                    Kws + (size_t)(j0 + kkey) * DH + kdim + j * 8);
                vreg[j] = *reinterpret_cast<const bf16x8*>(
                    Vtws + (size_t)vdim * SEQ + j0 + vkey + j * 8);
            }
            #pragma unroll
            for (int j = 0; j < 4; j++) {
                *reinterpret_cast<bf16x8*>(&Klds[kkey][kdim + j * 8]) = kreg[j];
                *reinterpret_cast<bf16x8*>(&Vlds[vdim][vkey + j * 8]) = vreg[j];
            }
        }
        lds_barrier();

        for (int jt = y; jt <= qb; jt += NSPLIT) {
            const bool more = (jt + NSPLIT <= qb);
            if (more) {
                const int jn = (jt + NSPLIT) * 64;
                #pragma unroll
                for (int j = 0; j < 4; j++) {
                    kreg[j] = *reinterpret_cast<const bf16x8*>(
                        Kws + (size_t)(jn + kkey) * DH + kdim + j * 8);
                    vreg[j] = *reinterpret_cast<const bf16x8*>(
                        Vtws + (size_t)vdim * SEQ + jn + vkey + j * 8);
                }
            }
            const int j0 = jt * 64;
            f32x4 S[4];
            #pragma unroll
            for (int t = 0; t < 4; t++) S[t] = (f32x4){0.f, 0.f, 0.f, 0.f};
            #pragma unroll
            for (int kk = 0; kk < 4; kk++) {
                #pragma unroll
                for (int t = 0; t < 4; t++) {
                    bf16x8 kf = *reinterpret_cast<const bf16x8*>(
                        &Klds[t * 16 + c16][kk * 32 + g * 8]);
                    S[t] = __builtin_amdgcn_mfma_f32_16x16x32_bf16(qf[kk], kf, S[t], 0, 0, 0);
                }
            }
            float s2[4][4];
            #pragma unroll
            for (int t = 0; t < 4; t++) {
                int key = j0 + t * 16 + c16;
                #pragma unroll
                for (int r = 0; r < 4; r++) {
                    int q = i0 + g * 4 + r;
                    s2[t][r] = (key > q) ? -__builtin_inff() : S[t][r] * C;
                }
            }
            float mnew[4], alpha[4];
            #pragma unroll
            for (int r = 0; r < 4; r++) {
                float rm = fmaxf(fmaxf(s2[0][r], s2[1][r]), fmaxf(s2[2][r], s2[3][r]));
                rm = fmaxf(rm, __shfl_xor(rm, 1));
                rm = fmaxf(rm, __shfl_xor(rm, 2));
                rm = fmaxf(rm, __shfl_xor(rm, 4));
                rm = fmaxf(rm, __shfl_xor(rm, 8));
                mnew[r] = fmaxf(m[r], rm);
                alpha[r] = fexp2(m[r] - mnew[r]);
                m[r] = mnew[r];
            }
            #pragma unroll
            for (int r = 0; r < 4; r++) {
                float ps = 0.f;
                #pragma unroll
                for (int t = 0; t < 4; t++) {
                    float p = fexp2(s2[t][r] - mnew[r]);
                    ps += p;
                    Slds[w][g * 4 + r][t * 16 + c16] = f2bf(p);
                }
                ps += __shfl_xor(ps, 1);
                ps += __shfl_xor(ps, 2);
                ps += __shfl_xor(ps, 4);
                ps += __shfl_xor(ps, 8);
                lsum[r] = lsum[r] * alpha[r] + ps;
                #pragma unroll
                for (int c = 0; c < 8; c++) O[c][r] *= alpha[r];
            }
            #pragma unroll
            for (int kk2 = 0; kk2 < 2; kk2++) {
                bf16x8 pf = *reinterpret_cast<const bf16x8*>(&Slds[w][c16][kk2 * 32 + g * 8]);
                #pragma unroll
                for (int c = 0; c < 8; c++) {
                    bf16x8 vf = *reinterpret_cast<const bf16x8*>(
                        &Vlds[c * 16 + c16][kk2 * 32 + g * 8]);
                    O[c] = __builtin_amdgcn_mfma_f32_16x16x32_bf16(pf, vf, O[c], 0, 0, 0);
                }
            }
            lds_barrier();               // readers done with Klds/Vlds
            if (more) {
                #pragma unroll
                for (int j = 0; j < 4; j++) {
                    *reinterpret_cast<bf16x8*>(&Klds[kkey][kdim + j * 8]) = kreg[j];
                    *reinterpret_cast<bf16x8*>(&Vlds[vdim][vkey + j * 8]) = vreg[j];
                }
                lds_barrier();           // writes visible before next compute
            }
        }
        #pragma unroll
        for (int c = 0; c < 8; c++) {
            int col = c * 16 + c16;
            #pragma unroll
            for (int r = 0; r < 4; r++)
                Opart[((size_t)y * SEQ + i0 + g * 4 + r) * DH + col] = O[c][r];
        }
    }
    if (c16 == 0) {
        #pragma unroll
        for (int r = 0; r < 4; r++) {
            mpart[y * SEQ + i0 + g * 4 + r] = m[r];
            lpart[y * SEQ + i0 + g * 4 + r] = lsum[r];
        }
    }
}

// ---------------- Merge NS split partials. grid 2048, block 256 (2 rows/block).
__global__ __launch_bounds__(256) void merge_kernel(
    const float* __restrict__ Opart, const float* __restrict__ mpart, const float* __restrict__ lpart,
    float* __restrict__ out, int NS)
{
    const int row = blockIdx.x * 2 + (threadIdx.x >> 7);
    const int col = threadIdx.x & 127;
    float mh[16];
    float M = -__builtin_inff();
    for (int hh = 0; hh < NS; hh++) {
        mh[hh] = mpart[hh * SEQ + row];
        M = fmaxf(M, mh[hh]);
    }
    float denom = 0.f, num = 0.f;
    for (int hh = 0; hh < NS; hh++) {
        float wgt = fexp2(mh[hh] - M);
        denom += lpart[hh * SEQ + row] * wgt;
        num   += Opart[((size_t)hh * SEQ + row) * DH + col] * wgt;
    }
    out[(size_t)row * DH + col] = num / denom;
}

extern "C" void kernel_launch(void* const* d_in, const int* in_sizes, int n_in,
                              void* d_out, int out_size, void* d_ws, size_t ws_size,
                              hipStream_t stream) {
    const float* inq = (const float*)d_in[0];
    const float* ink = (const float*)d_in[1];
    const float* inv = (const float*)d_in[2];
    const float* wq  = (const float*)d_in[3];
    const float* bq  = (const float*)d_in[4];
    const float* wk  = (const float*)d_in[5];
    const float* bk  = (const float*)d_in[6];
    const float* wv  = (const float*)d_in[7];
    const float* bv  = (const float*)d_in[8];

    char* ws = (char*)d_ws;
    short* Qws   = (short*)(ws);                         // [0, 1 MB)
    short* Kws   = (short*)(ws + (1u << 20));            // [1, 2 MB)
    short* Vtws  = (short*)(ws + (2u << 20));            // [2, 3 MB)  ([128][4096])
    short* Wbf   = (short*)(ws + (3u << 20));            // [3, 4.5 MB) bf16 W (proj-only)
    float* Opart = (float*)(ws + 4718592);               // [4.5, 20.5 MB)
    float* mpart = (float*)(ws + 4718592 + (size_t)NSPLIT * SEQ * DH * 4);
    float* lpart = mpart + (size_t)NSPLIT * SEQ;

    convw_kernel<<<768, 256, 0, stream>>>(wq, wk, wv, Wbf);
    proj_kernel<<<dim3(256, 3), 256, 0, stream>>>(inq, ink, inv, Wbf, bq, bk, bv, Qws, Kws, Vtws);
    flash_kernel<<<dim3(64, NSPLIT), 256, 0, stream>>>(Qws, Kws, Vtws, Opart, mpart, lpart);
    merge_kernel<<<2048, 256, 0, stream>>>(Opart, mpart, lpart, (float*)d_out, NSPLIT);
}

// Round 3
// 180.240 us; speedup vs baseline: 1.1390x; 1.1390x over previous
//
#include <hip/hip_runtime.h>

#define SEQ 4096
#define DM  2048
#define DH  128
#define NSPLIT 8

typedef __attribute__((ext_vector_type(8))) short bf16x8;
typedef __attribute__((ext_vector_type(4))) short short4v;
typedef __attribute__((ext_vector_type(4))) float f32x4;

__device__ inline short f2bf(float f) {
    union { float f; unsigned u; } x; x.f = f;
    unsigned r = x.u + 0x7fffu + ((x.u >> 16) & 1u);
    return (short)(r >> 16);
}

__device__ inline float fexp2(float f) { return __builtin_amdgcn_exp2f(f); }

// Barrier that does NOT drain outstanding global->VGPR loads (only LDS ops).
// __syncthreads() would emit s_waitcnt vmcnt(0) and collapse register prefetch.
__device__ inline void lds_barrier() {
    asm volatile("s_waitcnt lgkmcnt(0)\n\ts_barrier" ::: "memory");
}

// ---------------- W fp32 -> bf16 pre-convert. grid 768, block 256. Wbf[3][128][2048]
__global__ __launch_bounds__(256) void convw_kernel(
    const float* __restrict__ wq, const float* __restrict__ wk, const float* __restrict__ wv,
    short* __restrict__ Wbf)
{
    int idx = blockIdx.x * 256 + threadIdx.x;
    int mat = idx >> 16;
    int off = (idx & 65535) * 4;
    const float* W = (mat == 0) ? wq : (mat == 1) ? wk : wv;
    float4 v = *reinterpret_cast<const float4*>(W + off);
    short4v s = { f2bf(v.x), f2bf(v.y), f2bf(v.z), f2bf(v.w) };
    *reinterpret_cast<short4v*>(Wbf + (size_t)mat * DH * DM + off) = s;
}

// ---------------- Projection, split-K x4 (exact R0 structure -- the only variant
// whose register pipeline survives codegen). grid (64, 3, 4), block 256 (4 waves).
// Block tile: 64 rows x 128 cols, K-range 512, BK=64 (8 chunks).
// Depth-4 A prefetch (HBM) + depth-2 W prefetch (L2) survive the K-loop
// because lds_barrier() does not drain vmcnt.
__global__ __launch_bounds__(256) void proj_kernel(
    const float* __restrict__ inq, const float* __restrict__ ink, const float* __restrict__ inv,
    const short* __restrict__ Wbf,
    float* __restrict__ Pqk, float* __restrict__ Pv)
{
    const int mat = blockIdx.y;
    const int s   = blockIdx.z;
    const float* A = (mat == 0) ? inq : (mat == 1) ? ink : inv;

    const int tid  = threadIdx.x;
    const int lane = tid & 63;
    const int w    = tid >> 6;
    const int g    = lane >> 4;
    const int c16  = lane & 15;
    const int i0   = blockIdx.x * 64;
    const int kb   = s * 512;

    __shared__ short Alds[64][72];
    __shared__ short Wlds[128][72];

    const int ar = tid >> 2, ac = (tid & 3) * 16;
    const float* Aload = A + (size_t)(i0 + ar) * DM + kb + ac;
    const int wr = tid >> 1, wc = (tid & 1) * 32;
    const short* Wload = Wbf + (size_t)mat * DH * DM + (size_t)wr * DM + kb + wc;

    f32x4 acc[2][4];
    #pragma unroll
    for (int mI = 0; mI < 2; mI++)
        #pragma unroll
        for (int n = 0; n < 4; n++) acc[mI][n] = (f32x4){0.f, 0.f, 0.f, 0.f};

    float4  abuf[4][4];   // depth 4
    bf16x8  wbuf[2][4];   // depth 2

    #pragma unroll
    for (int d = 0; d < 2; d++) {
        #pragma unroll
        for (int j = 0; j < 4; j++)
            wbuf[d][j] = *reinterpret_cast<const bf16x8*>(Wload + d * 64 + j * 8);
        #pragma unroll
        for (int j = 0; j < 4; j++)
            abuf[d][j] = *reinterpret_cast<const float4*>(Aload + d * 64 + j * 4);
    }
    #pragma unroll
    for (int d = 2; d < 4; d++)
        #pragma unroll
        for (int j = 0; j < 4; j++)
            abuf[d][j] = *reinterpret_cast<const float4*>(Aload + d * 64 + j * 4);

    const int rw = (w >> 1) * 32;
    const int cw = (w & 1) * 64;

    #pragma unroll
    for (int c = 0; c < 8; c++) {
        const int da = c & 3, dw = c & 1;
        {
            #pragma unroll
            for (int j = 0; j < 4; j++)
                *reinterpret_cast<bf16x8*>(&Wlds[wr][wc + j * 8]) = wbuf[dw][j];
            #pragma unroll
            for (int j = 0; j < 2; j++) {
                float4 v0 = abuf[da][j * 2], v1 = abuf[da][j * 2 + 1];
                bf16x8 sv = { f2bf(v0.x), f2bf(v0.y), f2bf(v0.z), f2bf(v0.w),
                              f2bf(v1.x), f2bf(v1.y), f2bf(v1.z), f2bf(v1.w) };
                *reinterpret_cast<bf16x8*>(&Alds[ar][ac + j * 8]) = sv;
            }
        }
        if (c + 2 < 8) {
            #pragma unroll
            for (int j = 0; j < 4; j++)
                wbuf[dw][j] = *reinterpret_cast<const bf16x8*>(Wload + (c + 2) * 64 + j * 8);
        }
        if (c + 4 < 8) {
            #pragma unroll
            for (int j = 0; j < 4; j++)
                abuf[da][j] = *reinterpret_cast<const float4*>(Aload + (c + 4) * 64 + j * 4);
        }
        lds_barrier();
        #pragma unroll
        for (int kk = 0; kk < 2; kk++) {
            bf16x8 af0 = *reinterpret_cast<const bf16x8*>(&Alds[rw + c16][kk * 32 + g * 8]);
            bf16x8 af1 = *reinterpret_cast<const bf16x8*>(&Alds[rw + 16 + c16][kk * 32 + g * 8]);
            #pragma unroll
            for (int n = 0; n < 4; n++) {
                bf16x8 wf = *reinterpret_cast<const bf16x8*>(
                    &Wlds[cw + n * 16 + c16][kk * 32 + g * 8]);
                acc[0][n] = __builtin_amdgcn_mfma_f32_16x16x32_bf16(af0, wf, acc[0][n], 0, 0, 0);
                acc[1][n] = __builtin_amdgcn_mfma_f32_16x16x32_bf16(af1, wf, acc[1][n], 0, 0, 0);
            }
        }
        lds_barrier();
    }

    if (mat < 2) {
        float* outp = Pqk + ((size_t)(mat * 4 + s) * SEQ) * DH;
        #pragma unroll
        for (int mI = 0; mI < 2; mI++) {
            int row0 = i0 + rw + mI * 16 + g * 4;
            #pragma unroll
            for (int n = 0; n < 4; n++) {
                int col = cw + n * 16 + c16;
                #pragma unroll
                for (int r = 0; r < 4; r++)
                    outp[(size_t)(row0 + r) * DH + col] = acc[mI][n][r];
            }
        }
    } else {
        float* outp = Pv + (size_t)s * DH * SEQ;
        #pragma unroll
        for (int mI = 0; mI < 2; mI++) {
            int row0 = i0 + rw + mI * 16 + g * 4;
            #pragma unroll
            for (int n = 0; n < 4; n++) {
                int col = cw + n * 16 + c16;
                float4 f = { acc[mI][n][0], acc[mI][n][1], acc[mI][n][2], acc[mI][n][3] };
                *reinterpret_cast<float4*>(&outp[(size_t)col * SEQ + row0]) = f;
            }
        }
    }
}

// ---------------- Combine 4 split-K partials + bias -> bf16 Q, K, Vt. grid 1536.
__global__ __launch_bounds__(256) void combine_kernel(
    const float* __restrict__ Pqk, const float* __restrict__ Pv,
    const float* __restrict__ bq, const float* __restrict__ bk, const float* __restrict__ bv,
    short* __restrict__ Qws, short* __restrict__ Kws, short* __restrict__ Vtws)
{
    const int b = blockIdx.x;
    if (b < 1024) {
        int tid = b * 256 + threadIdx.x;
        int mat = tid >> 17;
        int idx4 = (tid & 131071) * 4;
        float4 acc = {0.f, 0.f, 0.f, 0.f};
        #pragma unroll
        for (int s = 0; s < 4; s++) {
            float4 p = *reinterpret_cast<const float4*>(
                Pqk + ((size_t)(mat * 4 + s) * SEQ) * DH + idx4);
            acc.x += p.x; acc.y += p.y; acc.z += p.z; acc.w += p.w;
        }
        const float* bias = (mat == 0) ? bq : bk;
        int col = idx4 & (DH - 1);
        acc.x += bias[col]; acc.y += bias[col + 1]; acc.z += bias[col + 2]; acc.w += bias[col + 3];
        short4v o = { f2bf(acc.x), f2bf(acc.y), f2bf(acc.z), f2bf(acc.w) };
        short* outp = (mat == 0) ? Qws : Kws;
        *reinterpret_cast<short4v*>(outp + idx4) = o;
    } else {
        int tid = (b - 1024) * 256 + threadIdx.x;
        int idx4 = tid * 4;
        float4 acc = {0.f, 0.f, 0.f, 0.f};
        #pragma unroll
        for (int s = 0; s < 4; s++) {
            float4 p = *reinterpret_cast<const float4*>(Pv + (size_t)s * DH * SEQ + idx4);
            acc.x += p.x; acc.y += p.y; acc.z += p.z; acc.w += p.w;
        }
        float bvv = bv[idx4 >> 12];
        acc.x += bvv; acc.y += bvv; acc.z += bvv; acc.w += bvv;
        short4v o = { f2bf(acc.x), f2bf(acc.y), f2bf(acc.z), f2bf(acc.w) };
        *reinterpret_cast<short4v*>(Vtws + idx4) = o;
    }
}

// ---------------- Flash attention, block-cooperative K/V staging, vmcnt-preserving
// barriers. grid 512 (1D), block 256 (4 waves).
// Load-balance remap: dispatch is linear, CU c gets bid=c and bid=c+256 (same
// qb-slot, y differing by 4). Per-block work = ceil((qb-y+1)/8) in [1..8], so
// reversing qb for y>=4 pairs heavy with light: w(qb,y)+w(63-qb,y+4) ~ const.
__global__ __launch_bounds__(256) void flash_kernel(
    const short* __restrict__ Qws, const short* __restrict__ Kws, const short* __restrict__ Vtws,
    float* __restrict__ Opart, float* __restrict__ mpart, float* __restrict__ lpart)
{
    const int bid = blockIdx.x;
    const int y   = bid >> 6;
    const int qbr = bid & 63;
    const int qb  = (y >= 4) ? (63 - qbr) : qbr;
    const int tid = threadIdx.x;
    const int w    = tid >> 6;
    const int lane = tid & 63;
    const int g = lane >> 4, c16 = lane & 15;
    const int i0 = qb * 64 + w * 16;

    __shared__ short Klds[64][136];
    __shared__ short Vlds[128][72];
    __shared__ short Slds[4][16][72];

    const int kkey = tid >> 2,  kdim = (tid & 3) * 32;
    const int vdim = tid >> 1,  vkey = (tid & 1) * 32;

    bf16x8 kreg[4], vreg[4];

    bf16x8 qf[4];
    #pragma unroll
    for (int kk = 0; kk < 4; kk++)
        qf[kk] = *reinterpret_cast<const bf16x8*>(Qws + (size_t)(i0 + c16) * DH + kk * 32 + g * 8);

    float m[4], lsum[4];
    f32x4 O[8];
    #pragma unroll
    for (int r = 0; r < 4; r++) { m[r] = -__builtin_inff(); lsum[r] = 0.f; }
    #pragma unroll
    for (int c = 0; c < 8; c++) O[c] = (f32x4){0.f, 0.f, 0.f, 0.f};

    const float C = 0.03188448666f;      // log2(e)/sqrt(2048)

    if (qb >= y) {
        {
            const int j0 = y * 64;
            #pragma unroll
            for (int j = 0; j < 4; j++) {
                kreg[j] = *reinterpret_cast<const bf16x8*>(
                    Kws + (size_t)(j0 + kkey) * DH + kdim + j * 8);
                vreg[j] = *reinterpret_cast<const bf16x8*>(
                    Vtws + (size_t)vdim * SEQ + j0 + vkey + j * 8);
            }
            #pragma unroll
            for (int j = 0; j < 4; j++) {
                *reinterpret_cast<bf16x8*>(&Klds[kkey][kdim + j * 8]) = kreg[j];
                *reinterpret_cast<bf16x8*>(&Vlds[vdim][vkey + j * 8]) = vreg[j];
            }
        }
        lds_barrier();

        for (int jt = y; jt <= qb; jt += NSPLIT) {
            const bool more = (jt + NSPLIT <= qb);
            if (more) {
                const int jn = (jt + NSPLIT) * 64;
                #pragma unroll
                for (int j = 0; j < 4; j++) {
                    kreg[j] = *reinterpret_cast<const bf16x8*>(
                        Kws + (size_t)(jn + kkey) * DH + kdim + j * 8);
                    vreg[j] = *reinterpret_cast<const bf16x8*>(
                        Vtws + (size_t)vdim * SEQ + jn + vkey + j * 8);
                }
            }
            const int j0 = jt * 64;
            f32x4 S[4];
            #pragma unroll
            for (int t = 0; t < 4; t++) S[t] = (f32x4){0.f, 0.f, 0.f, 0.f};
            __builtin_amdgcn_s_setprio(1);
            #pragma unroll
            for (int kk = 0; kk < 4; kk++) {
                #pragma unroll
                for (int t = 0; t < 4; t++) {
                    bf16x8 kf = *reinterpret_cast<const bf16x8*>(
                        &Klds[t * 16 + c16][kk * 32 + g * 8]);
                    S[t] = __builtin_amdgcn_mfma_f32_16x16x32_bf16(qf[kk], kf, S[t], 0, 0, 0);
                }
            }
            __builtin_amdgcn_s_setprio(0);
            float s2[4][4];
            #pragma unroll
            for (int t = 0; t < 4; t++) {
                int key = j0 + t * 16 + c16;
                #pragma unroll
                for (int r = 0; r < 4; r++) {
                    int q = i0 + g * 4 + r;
                    s2[t][r] = (key > q) ? -__builtin_inff() : S[t][r] * C;
                }
            }
            float mnew[4], alpha[4];
            #pragma unroll
            for (int r = 0; r < 4; r++) {
                float rm = fmaxf(fmaxf(s2[0][r], s2[1][r]), fmaxf(s2[2][r], s2[3][r]));
                rm = fmaxf(rm, __shfl_xor(rm, 1));
                rm = fmaxf(rm, __shfl_xor(rm, 2));
                rm = fmaxf(rm, __shfl_xor(rm, 4));
                rm = fmaxf(rm, __shfl_xor(rm, 8));
                mnew[r] = fmaxf(m[r], rm);
                alpha[r] = fexp2(m[r] - mnew[r]);
                m[r] = mnew[r];
            }
            #pragma unroll
            for (int r = 0; r < 4; r++) {
                float ps = 0.f;
                #pragma unroll
                for (int t = 0; t < 4; t++) {
                    float p = fexp2(s2[t][r] - mnew[r]);
                    ps += p;
                    Slds[w][g * 4 + r][t * 16 + c16] = f2bf(p);
                }
                ps += __shfl_xor(ps, 1);
                ps += __shfl_xor(ps, 2);
                ps += __shfl_xor(ps, 4);
                ps += __shfl_xor(ps, 8);
                lsum[r] = lsum[r] * alpha[r] + ps;
                #pragma unroll
                for (int c = 0; c < 8; c++) O[c][r] *= alpha[r];
            }
            __builtin_amdgcn_s_setprio(1);
            #pragma unroll
            for (int kk2 = 0; kk2 < 2; kk2++) {
                bf16x8 pf = *reinterpret_cast<const bf16x8*>(&Slds[w][c16][kk2 * 32 + g * 8]);
                #pragma unroll
                for (int c = 0; c < 8; c++) {
                    bf16x8 vf = *reinterpret_cast<const bf16x8*>(
                        &Vlds[c * 16 + c16][kk2 * 32 + g * 8]);
                    O[c] = __builtin_amdgcn_mfma_f32_16x16x32_bf16(pf, vf, O[c], 0, 0, 0);
                }
            }
            __builtin_amdgcn_s_setprio(0);
            lds_barrier();               // readers done with Klds/Vlds
            if (more) {
                #pragma unroll
                for (int j = 0; j < 4; j++) {
                    *reinterpret_cast<bf16x8*>(&Klds[kkey][kdim + j * 8]) = kreg[j];
                    *reinterpret_cast<bf16x8*>(&Vlds[vdim][vkey + j * 8]) = vreg[j];
                }
                lds_barrier();           // writes visible before next compute
            }
        }
        #pragma unroll
        for (int c = 0; c < 8; c++) {
            int col = c * 16 + c16;
            #pragma unroll
            for (int r = 0; r < 4; r++)
                Opart[((size_t)y * SEQ + i0 + g * 4 + r) * DH + col] = O[c][r];
        }
    }
    if (c16 == 0) {
        #pragma unroll
        for (int r = 0; r < 4; r++) {
            mpart[y * SEQ + i0 + g * 4 + r] = m[r];
            lpart[y * SEQ + i0 + g * 4 + r] = lsum[r];
        }
    }
}

// ---------------- Merge NS split partials. grid 2048, block 256 (2 rows/block).
__global__ __launch_bounds__(256) void merge_kernel(
    const float* __restrict__ Opart, const float* __restrict__ mpart, const float* __restrict__ lpart,
    float* __restrict__ out, int NS)
{
    const int row = blockIdx.x * 2 + (threadIdx.x >> 7);
    const int col = threadIdx.x & 127;
    float mh[16];
    float M = -__builtin_inff();
    for (int hh = 0; hh < NS; hh++) {
        mh[hh] = mpart[hh * SEQ + row];
        M = fmaxf(M, mh[hh]);
    }
    float denom = 0.f, num = 0.f;
    for (int hh = 0; hh < NS; hh++) {
        float wgt = fexp2(mh[hh] - M);
        denom += lpart[hh * SEQ + row] * wgt;
        num   += Opart[((size_t)hh * SEQ + row) * DH + col] * wgt;
    }
    out[(size_t)row * DH + col] = num / denom;
}

extern "C" void kernel_launch(void* const* d_in, const int* in_sizes, int n_in,
                              void* d_out, int out_size, void* d_ws, size_t ws_size,
                              hipStream_t stream) {
    const float* inq = (const float*)d_in[0];
    const float* ink = (const float*)d_in[1];
    const float* inv = (const float*)d_in[2];
    const float* wq  = (const float*)d_in[3];
    const float* bq  = (const float*)d_in[4];
    const float* wk  = (const float*)d_in[5];
    const float* bk  = (const float*)d_in[6];
    const float* wv  = (const float*)d_in[7];
    const float* bv  = (const float*)d_in[8];

    char* ws = (char*)d_ws;
    short* Qws   = (short*)(ws);                         // [0, 1 MB)
    short* Kws   = (short*)(ws + (1u << 20));            // [1, 2 MB)
    short* Vtws  = (short*)(ws + (2u << 20));            // [2, 3 MB)  ([128][4096])
    short* Wbf   = (short*)(ws + (3u << 20));            // [3, 4.5 MB) bf16 W (proj-only)
    float* Pqk   = (float*)(ws + 4718592);               // [4.5, 20.5 MB)
    float* Pv    = (float*)(ws + 21495808);              // [20.5, 28.5 MB)
    float* Opart = (float*)(ws + (3u << 20));            // aliases Wbf/Pqk (dead by flash)
    float* mpart = (float*)(ws + (3u << 20) + (size_t)NSPLIT * SEQ * DH * 4);
    float* lpart = mpart + (size_t)NSPLIT * SEQ;

    convw_kernel<<<768, 256, 0, stream>>>(wq, wk, wv, Wbf);
    proj_kernel<<<dim3(64, 3, 4), 256, 0, stream>>>(inq, ink, inv, Wbf, Pqk, Pv);
    combine_kernel<<<1536, 256, 0, stream>>>(Pqk, Pv, bq, bk, bv, Qws, Kws, Vtws);
    flash_kernel<<<512, 256, 0, stream>>>(Qws, Kws, Vtws, Opart, mpart, lpart);
    merge_kernel<<<2048, 256, 0, stream>>>(Opart, mpart, lpart, (float*)d_out, NSPLIT);
}